// Round 5
// baseline (352.833 us; speedup 1.0000x reference)
//
#include <hip/hip_runtime.h>
#include <hip/hip_bf16.h>
#include <math.h>

#define BB 4
#define NTOK 1024
#define DIMD 512
#define HH 8
#define DH 64
#define INNER 512
#define BH (BB*HH)          // 32
#define ROWS (BB*NTOK)      // 4096
#define SCALE 0.125f
#define INV_TEMP 10.0f

typedef __bf16 bf16_t;
using bf16x4 = __attribute__((ext_vector_type(4))) __bf16;
using bf16x8 = __attribute__((ext_vector_type(8))) __bf16;
using f32x4  = __attribute__((ext_vector_type(4))) float;

// ---------------------------------------------------------------------------
// MFMA GEMM core for the projection GEMMs: C[TM,TN] += A[TM,K]*B[TN,K]^T.
// LDS rows padded to 40 bf16 (20 banks): quarter-wave b128 frag reads are
// 2-way (free) instead of 8-way (2.94x) at stride 32.
// ---------------------------------------------------------------------------
template<int TM, int TN, int MT, int NT>
__device__ __forceinline__ void gemm_core(
    const bf16_t* __restrict__ A, int ldA,
    const bf16_t* __restrict__ B, int ldB, int K,
    bf16_t* As, bf16_t* Bs, f32x4 (&acc)[MT][NT])
{
    const int t = threadIdx.x;
    const int w = t >> 6, l = t & 63;
    constexpr int WGN = TN / (NT * 16);
    const int wm = w / WGN, wn = w % WGN;
    const int lrow = l & 15, lk = (l >> 4) * 8;

    for (int k0 = 0; k0 < K; k0 += 32) {
        #pragma unroll
        for (int it = 0; it < TM / 64; ++it) {
            int r = (t >> 2) + it * 64;
            *(uint4*)&As[r * 40 + (t & 3) * 8] =
                *(const uint4*)&A[(size_t)r * ldA + k0 + (t & 3) * 8];
        }
        #pragma unroll
        for (int it = 0; it < TN / 64; ++it) {
            int r = (t >> 2) + it * 64;
            *(uint4*)&Bs[r * 40 + (t & 3) * 8] =
                *(const uint4*)&B[(size_t)r * ldB + k0 + (t & 3) * 8];
        }
        __syncthreads();
        bf16x8 af[MT], bf[NT];
        #pragma unroll
        for (int mt = 0; mt < MT; ++mt)
            af[mt] = *(const bf16x8*)&As[(wm * MT * 16 + mt * 16 + lrow) * 40 + lk];
        #pragma unroll
        for (int nt = 0; nt < NT; ++nt)
            bf[nt] = *(const bf16x8*)&Bs[(wn * NT * 16 + nt * 16 + lrow) * 40 + lk];
        #pragma unroll
        for (int mt = 0; mt < MT; ++mt)
            #pragma unroll
            for (int nt = 0; nt < NT; ++nt)
                acc[mt][nt] = __builtin_amdgcn_mfma_f32_16x16x32_bf16(
                    af[mt], bf[nt], acc[mt][nt], 0, 0, 0);
        __syncthreads();
    }
}

// ---------------------------------------------------------------------------
__global__ __launch_bounds__(256) void convert_x(
    const float* __restrict__ x, bf16_t* __restrict__ xb)
{
    int idx = blockIdx.x * 256 + threadIdx.x;
    float4 v = ((const float4*)x)[idx];
    bf16x4 o = { (bf16_t)v.x, (bf16_t)v.y, (bf16_t)v.z, (bf16_t)v.w };
    ((bf16x4*)xb)[idx] = o;
}

__global__ __launch_bounds__(256) void mask_to_u8(
    const int* __restrict__ m, unsigned char* __restrict__ m8)
{
    int idx = blockIdx.x * 256 + threadIdx.x;
    int4 v = ((const int4*)m)[idx];
    uchar4 o = { (unsigned char)v.x, (unsigned char)v.y,
                 (unsigned char)v.z, (unsigned char)v.w };
    ((uchar4*)m8)[idx] = o;
}

// ---------------------------------------------------------------------------
__global__ __launch_bounds__(256) void transpose_w(
    const float* __restrict__ Wq, const float* __restrict__ Wk,
    const float* __restrict__ Wv, const float* __restrict__ Wo,
    bf16_t* __restrict__ wt)
{
    __shared__ float tile[32][33];
    const int z = blockIdx.z;
    const float* src = (z == 0) ? Wq : (z == 1) ? Wk : (z == 2) ? Wv : Wo;
    bf16_t* dst = wt + (size_t)z * DIMD * INNER;
    const int t = threadIdx.x, tx = t & 31, ty = t >> 5;
    const int rBase = blockIdx.y * 32, cBase = blockIdx.x * 32;
    #pragma unroll
    for (int i = 0; i < 4; ++i)
        tile[ty + i * 8][tx] = src[(size_t)(rBase + ty + i * 8) * INNER + cBase + tx];
    __syncthreads();
    #pragma unroll
    for (int i = 0; i < 4; ++i)
        dst[(size_t)(cBase + ty + i * 8) * DIMD + rBase + tx] = (bf16_t)tile[tx][ty + i * 8];
}

// ---------------------------------------------------------------------------
// QKV projection: xb[4096,512] @ Wt[z]^T + bias -> q/k (split-head), v (transposed)
// ---------------------------------------------------------------------------
__global__ __launch_bounds__(256) void qkv_gemm(
    const bf16_t* __restrict__ xb, const bf16_t* __restrict__ wt,
    const float* __restrict__ bq, const float* __restrict__ bk,
    const float* __restrict__ bv,
    bf16_t* __restrict__ qb, bf16_t* __restrict__ kb, bf16_t* __restrict__ vt)
{
    __shared__ __align__(16) bf16_t As[128 * 40];
    __shared__ __align__(16) bf16_t Bs[128 * 40];
    const int z = blockIdx.z;
    const bf16_t* Bp = wt + (size_t)z * DIMD * INNER;
    const float* bias = (z == 0) ? bq : (z == 1) ? bk : bv;
    const int rowBase = blockIdx.y * 128, colBase = blockIdx.x * 128;

    f32x4 acc[4][4] = {};
    gemm_core<128, 128, 4, 4>(xb + (size_t)rowBase * DIMD, DIMD,
                              Bp + (size_t)colBase * DIMD, DIMD, DIMD,
                              As, Bs, acc);

    const int l = threadIdx.x & 63, w = threadIdx.x >> 6;
    const int wm = w >> 1, wn = w & 1;
    #pragma unroll
    for (int mt = 0; mt < 4; ++mt)
        #pragma unroll
        for (int nt = 0; nt < 4; ++nt)
            #pragma unroll
            for (int r = 0; r < 4; ++r) {
                int grow = rowBase + wm * 64 + mt * 16 + (l >> 4) * 4 + r;
                int gcol = colBase + wn * 64 + nt * 16 + (l & 15);
                float val = acc[mt][nt][r] + bias[gcol];
                int b = grow >> 10, n = grow & 1023, h = gcol >> 6, d = gcol & 63;
                if (z == 0)
                    qb[(((size_t)b * HH + h) * NTOK + n) * DH + d] = (bf16_t)val;
                else if (z == 1)
                    kb[(((size_t)b * HH + h) * NTOK + n) * DH + d] = (bf16_t)val;
                else
                    vt[(((size_t)b * HH + h) * DH + d) * NTOK + n] = (bf16_t)val;
            }
}

// ---------------------------------------------------------------------------
__global__ __launch_bounds__(256) void norm_kernel(
    const bf16_t* __restrict__ qb, const bf16_t* __restrict__ kb,
    float* __restrict__ qn, float* __restrict__ kn)
{
    const int row = blockIdx.x * 4 + (threadIdx.x >> 6);
    const int d = threadIdx.x & 63;
    const bf16_t* src = blockIdx.y ? kb : qb;
    float* dst = blockIdx.y ? kn : qn;
    float v = (float)src[(size_t)row * DH + d];
    float s = v * v;
    #pragma unroll
    for (int off = 32; off; off >>= 1) s += __shfl_down(s, off);
    if (d == 0) dst[row] = sqrtf(s);
}

// ---------------------------------------------------------------------------
// FUSED: scores (QK^T) -> DCL stats + masked softmax -> AV, one block per
// (bh, 32-row i-tile). Score strip lives in LDS (32x1028 fp32).
// R3 bugfix: phase R now covers all 1024 columns per wave-row (4 chunks of
// 64 lanes x float4); R3 only processed columns 0..255.
// ---------------------------------------------------------------------------
__global__ __launch_bounds__(256, 1) void fused_attn(
    const bf16_t* __restrict__ qb, const bf16_t* __restrict__ kb,
    const bf16_t* __restrict__ vt, const unsigned char* __restrict__ mask8,
    const float* __restrict__ qn, const float* __restrict__ kn,
    float* __restrict__ attnf, bf16_t* __restrict__ ctxb,
    float* __restrict__ cl, float* __restrict__ rg)
{
    __shared__ __align__(16) float  Ssc[32 * 1028];   // 131584 B
    __shared__ __align__(16) bf16_t KV[128 * 72];     // 18432 B (K chunk / V chunk)
    __shared__ __align__(16) bf16_t Qt[32 * 72];      // 4608 B
    const int t = threadIdx.x, l = t & 63, w = t >> 6;
    const int bh = blockIdx.y, i0 = blockIdx.x * 32;
    const int b = bh >> 3, h = bh & 7;
    const bf16_t* Q = qb + ((size_t)bh * NTOK + i0) * DH;
    const bf16_t* K = kb + (size_t)bh * NTOK * DH;
    const int lrow = l & 15, lq = l >> 4, lk = (l >> 4) * 8;

    // ---- stage Q tile (32x64) ----
    {
        int r = t >> 3, c = (t & 7) * 8;
        *(uint4*)&Qt[r * 72 + c] = *(const uint4*)&Q[(size_t)r * DH + c];
    }
    __syncthreads();

    // ---- phase S: scores into Ssc ----
    const int mt = w >> 1, wn = w & 1;   // row-tile of 16, col-half
    bf16x8 af0 = *(const bf16x8*)&Qt[(mt * 16 + lrow) * 72 + lk];
    bf16x8 af1 = *(const bf16x8*)&Qt[(mt * 16 + lrow) * 72 + 32 + lk];
    for (int jc = 0; jc < 8; ++jc) {
        const int j0 = jc * 128;
        #pragma unroll
        for (int it = 0; it < 4; ++it) {
            int r = (t >> 3) + it * 32, c = (t & 7) * 8;
            *(uint4*)&KV[r * 72 + c] = *(const uint4*)&K[(size_t)(j0 + r) * DH + c];
        }
        __syncthreads();
        #pragma unroll
        for (int ct = 0; ct < 4; ++ct) {
            int jt = wn * 4 + ct;
            bf16x8 b0 = *(const bf16x8*)&KV[(jt * 16 + lrow) * 72 + lk];
            bf16x8 b1 = *(const bf16x8*)&KV[(jt * 16 + lrow) * 72 + 32 + lk];
            f32x4 acc = {};
            acc = __builtin_amdgcn_mfma_f32_16x16x32_bf16(af0, b0, acc, 0, 0, 0);
            acc = __builtin_amdgcn_mfma_f32_16x16x32_bf16(af1, b1, acc, 0, 0, 0);
            #pragma unroll
            for (int r = 0; r < 4; ++r)
                Ssc[(mt * 16 + lq * 4 + r) * 1028 + j0 + jt * 16 + lrow] = acc[r];
        }
        __syncthreads();
    }

    // ---- phase R: DCL stats + masked softmax, wave-per-row, 4 col chunks ----
    f32x4 knc[4];
    #pragma unroll
    for (int cc = 0; cc < 4; ++cc)
        knc[cc] = *(const f32x4*)&kn[(size_t)bh * NTOK + cc * 256 + 4 * l];

    #pragma unroll 1
    for (int rr = 0; rr < 8; ++rr) {
        const int row = w + rr * 4;
        const int gi = i0 + row;
        const float qni = qn[(size_t)bh * NTOK + gi];
        f32x4 s4[4];
        uchar4 m4[4];
        #pragma unroll
        for (int cc = 0; cc < 4; ++cc) {
            s4[cc] = *(const f32x4*)&Ssc[row * 1028 + cc * 256 + 4 * l];
            m4[cc] = *(const uchar4*)&mask8[((size_t)b * NTOK + gi) * NTOK + cc * 256 + 4 * l];
        }
        float z[4][4];
        float pos = 0.f, alls = 0.f, zmax = -1e30f, reg = 0.f;
        #pragma unroll
        for (int cc = 0; cc < 4; ++cc) {
            const int mm[4] = { m4[cc].x, m4[cc].y, m4[cc].z, m4[cc].w };
            #pragma unroll
            for (int u = 0; u < 4; ++u) {
                float sv = s4[cc][u];
                float e = __expf(sv / (qni * knc[cc][u]) * INV_TEMP);
                alls += e;
                if (mm[u]) pos += e;
                reg += (float)mm[u];
                if (cc * 256 + 4 * l + u == gi) reg -= 2.0f * (float)mm[u];
                z[cc][u] = (mm[u] ? sv : -1.0e9f) * SCALE;
                zmax = fmaxf(zmax, z[cc][u]);
            }
        }
        #pragma unroll
        for (int off = 32; off; off >>= 1) {
            pos  += __shfl_xor(pos, off);
            alls += __shfl_xor(alls, off);
            reg  += __shfl_xor(reg, off);
            zmax = fmaxf(zmax, __shfl_xor(zmax, off));
        }
        float ex[4][4], esum = 0.f;
        #pragma unroll
        for (int cc = 0; cc < 4; ++cc)
            #pragma unroll
            for (int u = 0; u < 4; ++u) { ex[cc][u] = __expf(z[cc][u] - zmax); esum += ex[cc][u]; }
        #pragma unroll
        for (int off = 32; off; off >>= 1) esum += __shfl_xor(esum, off);
        const float inv = 1.0f / esum;
        #pragma unroll
        for (int cc = 0; cc < 4; ++cc) {
            f32x4 o4 = { ex[cc][0] * inv, ex[cc][1] * inv, ex[cc][2] * inv, ex[cc][3] * inv };
            *(f32x4*)&Ssc[row * 1028 + cc * 256 + 4 * l] = o4;
            *(f32x4*)&attnf[((size_t)bh * NTOK + gi) * NTOK + cc * 256 + 4 * l] = o4;
        }
        if (l == 0) {
            cl[(size_t)bh * NTOK + gi] = logf(alls) - logf(pos);
            if (h == 0) rg[(size_t)b * NTOK + gi] = reg + 1.0f;
        }
    }
    __syncthreads();

    // ---- phase AV: O[32,64] = P @ V^T (vt is [dh][n], K-fastest) ----
    const int dn = w & 1;                  // d-tile pair {2dn, 2dn+1}; row-tile mt
    f32x4 accO[2] = {};
    for (int jc = 0; jc < 8; ++jc) {
        const int j0 = jc * 128;
        #pragma unroll
        for (int it = 0; it < 4; ++it) {
            int d = (t >> 4) + it * 16, c = (t & 15) * 8;
            *(uint4*)&KV[d * 136 + c] =
                *(const uint4*)&vt[((size_t)bh * DH + d) * NTOK + j0 + c];
        }
        __syncthreads();
        #pragma unroll
        for (int kc = 0; kc < 4; ++kc) {
            const float* ps = &Ssc[(mt * 16 + lrow) * 1028 + j0 + kc * 32 + lk];
            f32x4 p0 = *(const f32x4*)ps;
            f32x4 p1 = *(const f32x4*)(ps + 4);
            bf16x8 afrag = { (bf16_t)p0[0], (bf16_t)p0[1], (bf16_t)p0[2], (bf16_t)p0[3],
                             (bf16_t)p1[0], (bf16_t)p1[1], (bf16_t)p1[2], (bf16_t)p1[3] };
            #pragma unroll
            for (int dt = 0; dt < 2; ++dt) {
                bf16x8 bfrag = *(const bf16x8*)&KV[((dn * 2 + dt) * 16 + lrow) * 136 + kc * 32 + lk];
                accO[dt] = __builtin_amdgcn_mfma_f32_16x16x32_bf16(afrag, bfrag, accO[dt], 0, 0, 0);
            }
        }
        __syncthreads();
    }
    #pragma unroll
    for (int dt = 0; dt < 2; ++dt)
        #pragma unroll
        for (int r = 0; r < 4; ++r) {
            int row = mt * 16 + lq * 4 + r;
            int d = (dn * 2 + dt) * 16 + lrow;
            ctxb[((size_t)b * NTOK + i0 + row) * INNER + h * DH + d] = (bf16_t)accO[dt][r];
        }
}

// ---------------------------------------------------------------------------
__device__ __forceinline__ float block_sum256(float v, float* sh)
{
    #pragma unroll
    for (int off = 32; off; off >>= 1) v += __shfl_down(v, off);
    __syncthreads();
    if ((threadIdx.x & 63) == 0) sh[threadIdx.x >> 6] = v;
    __syncthreads();
    return sh[0] + sh[1] + sh[2] + sh[3];
}

__global__ __launch_bounds__(256) void finalize_kernel(
    const float* __restrict__ cl, const float* __restrict__ rg,
    float* __restrict__ dcl)
{
    __shared__ float sh[4];
    float s1 = 0.f, s2 = 0.f;
    for (int idx = threadIdx.x; idx < BH * NTOK; idx += 256) s1 += cl[idx];
    for (int idx = threadIdx.x; idx < BB * NTOK; idx += 256) s2 += rg[idx];
    s1 = block_sum256(s1, sh);
    s2 = block_sum256(s2, sh);
    if (threadIdx.x == 0) {
        dcl[0] = s1 * (1.0f / (float)(BB * HH * NTOK))
               + 0.3f * s2 * (1.0f / ((float)NTOK * (float)(NTOK - 1) * (float)BB));
    }
}

// ---------------------------------------------------------------------------
// Out projection: ctxb[4096,512] @ Wo_t^T + bo -> fp32 out
// ---------------------------------------------------------------------------
__global__ __launch_bounds__(256) void out_gemm(
    const bf16_t* __restrict__ ctxb, const bf16_t* __restrict__ wt,
    const float* __restrict__ bo, float* __restrict__ outp)
{
    __shared__ __align__(16) bf16_t As[128 * 40];
    __shared__ __align__(16) bf16_t Bs[128 * 40];
    const int rowBase = blockIdx.y * 128, colBase = blockIdx.x * 128;
    const bf16_t* Wot = wt + (size_t)3 * DIMD * INNER;

    f32x4 acc[4][4] = {};
    gemm_core<128, 128, 4, 4>(ctxb + (size_t)rowBase * INNER, INNER,
                              Wot + (size_t)colBase * INNER, INNER, INNER,
                              As, Bs, acc);

    const int l = threadIdx.x & 63, w = threadIdx.x >> 6;
    const int wm = w >> 1, wn = w & 1;
    #pragma unroll
    for (int mt = 0; mt < 4; ++mt)
        #pragma unroll
        for (int nt = 0; nt < 4; ++nt)
            #pragma unroll
            for (int r = 0; r < 4; ++r) {
                int grow = rowBase + wm * 64 + mt * 16 + (l >> 4) * 4 + r;
                int gcol = colBase + wn * 64 + nt * 16 + (l & 15);
                outp[(size_t)grow * DIMD + gcol] = acc[mt][nt][r] + bo[gcol];
            }
}

// ---------------------------------------------------------------------------
extern "C" void kernel_launch(void* const* d_in, const int* in_sizes, int n_in,
                              void* d_out, int out_size, void* d_ws, size_t ws_size,
                              hipStream_t stream)
{
    const float* x  = (const float*)d_in[0];
    const int* mask = (const int*)d_in[1];
    const float* Wq = (const float*)d_in[2];
    const float* bq = (const float*)d_in[3];
    const float* Wk = (const float*)d_in[4];
    const float* bk = (const float*)d_in[5];
    const float* Wv = (const float*)d_in[6];
    const float* bv = (const float*)d_in[7];
    const float* Wo = (const float*)d_in[8];
    const float* bo = (const float*)d_in[9];

    float* out   = (float*)d_out;                        // [4096, 512]
    float* attnf = out + (size_t)ROWS * DIMD;            // [32,1024,1024] fp32
    float* dcl   = attnf + (size_t)BH * NTOK * NTOK;     // scalar

    char* wsb = (char*)d_ws;
    bf16_t* xb    = (bf16_t*)wsb;                              // 4 MB
    bf16_t* wt    = xb + (size_t)ROWS * DIMD;                  // 2 MB (4x 512x512)
    bf16_t* qb    = wt + (size_t)4 * DIMD * INNER;             // 4 MB
    bf16_t* kb    = qb + (size_t)BH * NTOK * DH;               // 4 MB
    bf16_t* vt    = kb + (size_t)BH * NTOK * DH;               // 4 MB
    bf16_t* ctxb  = vt + (size_t)BH * NTOK * DH;               // 4 MB
    unsigned char* mask8 = (unsigned char*)(ctxb + (size_t)ROWS * INNER); // 4 MB
    float*  qn    = (float*)(mask8 + (size_t)BB * NTOK * NTOK);
    float*  kn    = qn + BH * NTOK;
    float*  cl    = kn + BH * NTOK;
    float*  rg    = cl + BH * NTOK;

    dim3 blk(256);
    convert_x<<<dim3(ROWS * DIMD / 1024), blk, 0, stream>>>(x, xb);
    mask_to_u8<<<dim3(BB * NTOK * NTOK / 1024), blk, 0, stream>>>(mask, mask8);
    transpose_w<<<dim3(16, 16, 4), blk, 0, stream>>>(Wq, Wk, Wv, Wo, wt);
    qkv_gemm<<<dim3(4, 32, 3), blk, 0, stream>>>(xb, wt, bq, bk, bv, qb, kb, vt);
    norm_kernel<<<dim3(BH * NTOK / 4, 2), blk, 0, stream>>>(qb, kb, qn, kn);
    fused_attn<<<dim3(32, 32), blk, 0, stream>>>(qb, kb, vt, mask8, qn, kn,
                                                 attnf, ctxb, cl, rg);
    finalize_kernel<<<1, blk, 0, stream>>>(cl, rg, dcl);
    out_gemm<<<dim3(4, 32), blk, 0, stream>>>(ctxb, wt, bo, out);
}